// Round 1
// baseline (926.729 us; speedup 1.0000x reference)
//
#include <hip/hip_runtime.h>

#define SEQ 4096
#define HIDDEN 2048
#define NHEADS 16
#define HDIM 128

typedef float f32x4 __attribute__((ext_vector_type(4)));
typedef __bf16 bf16x8 __attribute__((ext_vector_type(8)));
typedef unsigned int u32x4 __attribute__((ext_vector_type(4)));
typedef unsigned short u16x8 __attribute__((ext_vector_type(8)));
typedef unsigned short u16;

__device__ __forceinline__ u16 f2bf(float f) {
  unsigned u = __float_as_uint(f);
  unsigned r = 0x7fffu + ((u >> 16) & 1u);
  return (u16)((u + r) >> 16);
}
__device__ __forceinline__ float bf2f(u16 u) {
  return __uint_as_float(((unsigned)u) << 16);
}

// ---------------- fp32 -> bf16 convert ----------------
__global__ __launch_bounds__(256) void cvt_kernel(const float* __restrict__ src,
                                                  u16* __restrict__ dst, int n) {
  int i = (blockIdx.x * 256 + threadIdx.x) * 8;
  if (i + 8 > n) return;
  float4 a = *reinterpret_cast<const float4*>(src + i);
  float4 b = *reinterpret_cast<const float4*>(src + i + 4);
  u16x8 o;
  o[0] = f2bf(a.x); o[1] = f2bf(a.y); o[2] = f2bf(a.z); o[3] = f2bf(a.w);
  o[4] = f2bf(b.x); o[5] = f2bf(b.y); o[6] = f2bf(b.z); o[7] = f2bf(b.w);
  *reinterpret_cast<u32x4*>(dst + i) = __builtin_bit_cast(u32x4, o);
}

// ---------------- GEMM: C[M][N] = A[M][K] * B[N][K]^T (bf16 in, fp32 acc) ----
// 128x128 tile, 4 waves (2x2), each wave 64x64 = 4x4 MFMA frags, BK=32.
template <int F32OUT>
__global__ __launch_bounds__(256) void gemm_bt(const u16* __restrict__ A,
                                               const u16* __restrict__ B,
                                               void* __restrict__ Cout,
                                               int M, int N, int K) {
  __shared__ u16 As[128 * 32];
  __shared__ u16 Bs[128 * 32];
  const int t = threadIdx.x;
  const int lane = t & 63;
  const int wave = t >> 6;
  const int wr = (wave >> 1) * 64;
  const int wc = (wave & 1) * 64;
  const int lrow = lane & 15;
  const int lk = (lane >> 4) * 8;
  const int bm = blockIdx.x * 128;
  const int bn = blockIdx.y * 128;
  const int r0 = t >> 2;        // staging row within tile (0..63), +64 for issue 1
  const int c0 = (t & 3) * 8;   // staging col

  f32x4 acc[4][4] = {};

  for (int kt = 0; kt < K; kt += 32) {
    u32x4 av[2], bv[2];
#pragma unroll
    for (int is = 0; is < 2; ++is) {
      av[is] = *reinterpret_cast<const u32x4*>(A + (size_t)(bm + is * 64 + r0) * K + kt + c0);
      bv[is] = *reinterpret_cast<const u32x4*>(B + (size_t)(bn + is * 64 + r0) * K + kt + c0);
    }
    __syncthreads();
#pragma unroll
    for (int is = 0; is < 2; ++is) {
      *reinterpret_cast<u32x4*>(&As[is * 2048 + t * 8]) = av[is];
      *reinterpret_cast<u32x4*>(&Bs[is * 2048 + t * 8]) = bv[is];
    }
    __syncthreads();
    bf16x8 af[4], bfv[4];
#pragma unroll
    for (int m = 0; m < 4; ++m)
      af[m] = __builtin_bit_cast(bf16x8,
          *reinterpret_cast<const u32x4*>(&As[(wr + m * 16 + lrow) * 32 + lk]));
#pragma unroll
    for (int n = 0; n < 4; ++n)
      bfv[n] = __builtin_bit_cast(bf16x8,
          *reinterpret_cast<const u32x4*>(&Bs[(wc + n * 16 + lrow) * 32 + lk]));
#pragma unroll
    for (int m = 0; m < 4; ++m)
#pragma unroll
      for (int n = 0; n < 4; ++n)
        acc[m][n] = __builtin_amdgcn_mfma_f32_16x16x32_bf16(af[m], bfv[n], acc[m][n], 0, 0, 0);
  }

  // epilogue: C row = (lane>>4)*4 + reg, col = lane&15
  const int rbase = (lane >> 4) * 4;
#pragma unroll
  for (int m = 0; m < 4; ++m) {
#pragma unroll
    for (int n = 0; n < 4; ++n) {
#pragma unroll
      for (int r = 0; r < 4; ++r) {
        int row = bm + wr + m * 16 + rbase + r;
        int col = bn + wc + n * 16 + lrow;
        if (F32OUT)
          ((float*)Cout)[(size_t)row * N + col] = acc[m][n][r];
        else
          ((u16*)Cout)[(size_t)row * N + col] = f2bf(acc[m][n][r]);
      }
    }
  }
}

// ---------------- RoPE (in-place on bf16 [S][H] tensor) ----------------
__global__ __launch_bounds__(256) void rope_kernel(u16* __restrict__ X) {
  int idx = blockIdx.x * 256 + threadIdx.x;  // SEQ*NHEADS*64
  int i = idx & 63;
  int h = (idx >> 6) & (NHEADS - 1);
  int s = idx >> 10;
  if (s >= SEQ) return;
  float inv_freq = powf(10000.0f, -(float)i * (1.0f / 64.0f));
  float ang = (float)s * inv_freq;
  float c = cosf(ang), sn = sinf(ang);
  size_t base = (size_t)s * HIDDEN + h * HDIM + i;
  float x1 = bf2f(X[base]);
  float x2 = bf2f(X[base + 64]);
  X[base] = f2bf(x1 * c - x2 * sn);
  X[base + 64] = f2bf(x2 * c + x1 * sn);
}

// ---------------- causal flash attention ----------------
// grid (SEQ/64, NHEADS); 4 waves/block, wave w owns q rows qtile*64+w*16 .. +15.
__global__ __launch_bounds__(256) void attn_kernel(const u16* __restrict__ Q,
                                                   const u16* __restrict__ Kg,
                                                   const u16* __restrict__ Vg,
                                                   u16* __restrict__ O) {
  __shared__ u16 Ks[32 * 128];
  __shared__ u16 Vs[32 * 128];
  __shared__ u16 Ps[4][16 * 32];
  const int t = threadIdx.x;
  const int wave = t >> 6;
  const int lane = t & 63;
  const int lrow = lane & 15;
  const int lgrp = lane >> 4;
  const int h = blockIdx.y;
  const int qtile = (int)gridDim.x - 1 - (int)blockIdx.x;  // heavy tiles first
  const int qb = qtile * 64 + wave * 16;

  // Q fragments (16 rows x 128 cols) -> 4 chunks of K=32
  bf16x8 qf[4];
#pragma unroll
  for (int kk = 0; kk < 4; ++kk)
    qf[kk] = __builtin_bit_cast(bf16x8, *reinterpret_cast<const u32x4*>(
        Q + (size_t)(qb + lrow) * HIDDEN + h * HDIM + kk * 32 + lgrp * 8));

  f32x4 acc[8] = {};
  float mrow[4] = {-1e30f, -1e30f, -1e30f, -1e30f};
  float lsum[4] = {0.f, 0.f, 0.f, 0.f};

  const int nblk = qtile * 2 + 2;
  for (int b = 0; b < nblk; ++b) {
    const int t0 = b * 32;
    // stage K/V tile [32][128]
    u32x4 kv[2], vv[2];
#pragma unroll
    for (int is = 0; is < 2; ++is) {
      int e = is * 2048 + t * 8;
      int rr = e >> 7, cc = e & 127;
      kv[is] = *reinterpret_cast<const u32x4*>(Kg + (size_t)(t0 + rr) * HIDDEN + h * HDIM + cc);
      vv[is] = *reinterpret_cast<const u32x4*>(Vg + (size_t)(t0 + rr) * HIDDEN + h * HDIM + cc);
    }
    __syncthreads();
#pragma unroll
    for (int is = 0; is < 2; ++is) {
      int e = is * 2048 + t * 8;
      *reinterpret_cast<u32x4*>(&Ks[e]) = kv[is];
      *reinterpret_cast<u32x4*>(&Vs[e]) = vv[is];
    }
    __syncthreads();

    if (t0 <= qb + 15) {  // wave-uniform: skip fully-masked KV blocks
      // scores 16x32 via 2 halves x 4 K-chunks
      f32x4 sc[2] = {};
#pragma unroll
      for (int half = 0; half < 2; ++half) {
#pragma unroll
        for (int kk = 0; kk < 4; ++kk) {
          bf16x8 kf = __builtin_bit_cast(bf16x8, *reinterpret_cast<const u32x4*>(
              &Ks[(half * 16 + lrow) * 128 + kk * 32 + lgrp * 8]));
          sc[half] = __builtin_amdgcn_mfma_f32_16x16x32_bf16(qf[kk], kf, sc[half], 0, 0, 0);
        }
      }
      // scale + causal mask; row max
      float pm[4];
#pragma unroll
      for (int r = 0; r < 4; ++r) {
        const int qg = qb + lgrp * 4 + r;
#pragma unroll
        for (int half = 0; half < 2; ++half) {
          const int tg = t0 + half * 16 + lrow;
          float v = sc[half][r] * 0.088388347648318447f;
          sc[half][r] = (tg <= qg) ? v : -1e30f;
        }
        pm[r] = fmaxf(sc[0][r], sc[1][r]);
      }
#pragma unroll
      for (int off = 1; off < 16; off <<= 1)
#pragma unroll
        for (int r = 0; r < 4; ++r)
          pm[r] = fmaxf(pm[r], __shfl_xor(pm[r], off));

      // online softmax update
      float psum[4];
      u16 pb[8];
#pragma unroll
      for (int r = 0; r < 4; ++r) {
        float mn = fmaxf(mrow[r], pm[r]);
        float sf = __expf(mrow[r] - mn);
        mrow[r] = mn;
        lsum[r] *= sf;
#pragma unroll
        for (int nn = 0; nn < 8; ++nn) acc[nn][r] *= sf;
        float p0 = __expf(sc[0][r] - mn);
        float p1 = __expf(sc[1][r] - mn);
        psum[r] = p0 + p1;
        pb[r] = f2bf(p0);
        pb[4 + r] = f2bf(p1);
      }
#pragma unroll
      for (int off = 1; off < 16; off <<= 1)
#pragma unroll
        for (int r = 0; r < 4; ++r)
          psum[r] += __shfl_xor(psum[r], off);
#pragma unroll
      for (int r = 0; r < 4; ++r) lsum[r] += psum[r];

      // P -> LDS (bf16), then PV
#pragma unroll
      for (int r = 0; r < 4; ++r) {
        Ps[wave][(lgrp * 4 + r) * 32 + lrow] = pb[r];
        Ps[wave][(lgrp * 4 + r) * 32 + 16 + lrow] = pb[4 + r];
      }
      bf16x8 pa = __builtin_bit_cast(bf16x8,
          *reinterpret_cast<const u32x4*>(&Ps[wave][lrow * 32 + lgrp * 8]));
#pragma unroll
      for (int nn = 0; nn < 8; ++nn) {
        u16x8 vt;
#pragma unroll
        for (int j = 0; j < 8; ++j)
          vt[j] = Vs[(lgrp * 8 + j) * 128 + nn * 16 + lrow];
        bf16x8 vb = __builtin_bit_cast(bf16x8, vt);
        acc[nn] = __builtin_amdgcn_mfma_f32_16x16x32_bf16(pa, vb, acc[nn], 0, 0, 0);
      }
    }
    __syncthreads();
  }

  // epilogue: divide by lsum, write ctx
#pragma unroll
  for (int nn = 0; nn < 8; ++nn) {
#pragma unroll
    for (int r = 0; r < 4; ++r) {
      int row = qb + lgrp * 4 + r;
      int col = h * HDIM + nn * 16 + lrow;
      O[(size_t)row * HIDDEN + col] = f2bf(acc[nn][r] / lsum[r]);
    }
  }
}

// ---------------- launch ----------------
extern "C" void kernel_launch(void* const* d_in, const int* in_sizes, int n_in,
                              void* d_out, int out_size, void* d_ws, size_t ws_size,
                              hipStream_t stream) {
  const float* X  = (const float*)d_in[0];
  const float* Wq = (const float*)d_in[1];
  const float* Wk = (const float*)d_in[2];
  const float* Wv = (const float*)d_in[3];
  const float* Wo = (const float*)d_in[4];
  float* out = (float*)d_out;

  u16* ws = (u16*)d_ws;
  const size_t SH = (size_t)SEQ * HIDDEN;
  const size_t HH = (size_t)HIDDEN * HIDDEN;
  u16* Xb  = ws;
  u16* Wqb = Xb + SH;
  u16* Wkb = Wqb + HH;
  u16* Wvb = Wkb + HH;
  u16* Wob = Wvb + HH;
  u16* Qb  = Wob + HH;
  u16* Kb  = Qb + SH;
  u16* Vb  = Kb + SH;
  u16* Cb  = Vb + SH;

  cvt_kernel<<<(int)(SH / 2048), 256, 0, stream>>>(X, Xb, (int)SH);
  cvt_kernel<<<(int)(HH / 2048), 256, 0, stream>>>(Wq, Wqb, (int)HH);
  cvt_kernel<<<(int)(HH / 2048), 256, 0, stream>>>(Wk, Wkb, (int)HH);
  cvt_kernel<<<(int)(HH / 2048), 256, 0, stream>>>(Wv, Wvb, (int)HH);
  cvt_kernel<<<(int)(HH / 2048), 256, 0, stream>>>(Wo, Wob, (int)HH);

  dim3 ggrid(SEQ / 128, HIDDEN / 128);
  gemm_bt<0><<<ggrid, 256, 0, stream>>>(Xb, Wqb, Qb, SEQ, HIDDEN, HIDDEN);
  gemm_bt<0><<<ggrid, 256, 0, stream>>>(Xb, Wkb, Kb, SEQ, HIDDEN, HIDDEN);
  gemm_bt<0><<<ggrid, 256, 0, stream>>>(Xb, Wvb, Vb, SEQ, HIDDEN, HIDDEN);

  const int ropeN = SEQ * NHEADS * 64;
  rope_kernel<<<ropeN / 256, 256, 0, stream>>>(Qb);
  rope_kernel<<<ropeN / 256, 256, 0, stream>>>(Kb);

  attn_kernel<<<dim3(SEQ / 64, NHEADS), 256, 0, stream>>>(Qb, Kb, Vb, Cb);

  gemm_bt<1><<<ggrid, 256, 0, stream>>>(Cb, Wob, out, SEQ, HIDDEN, HIDDEN);
}

// Round 2
// 599.453 us; speedup vs baseline: 1.5460x; 1.5460x over previous
//
#include <hip/hip_runtime.h>

#define SEQ 4096
#define HIDDEN 2048
#define NHEADS 16
#define HDIM 128
#define QBLK 128
#define WQ 32
#define KVB 64

typedef float f32x4 __attribute__((ext_vector_type(4)));
typedef __bf16 bf16x8 __attribute__((ext_vector_type(8)));
typedef unsigned int u32x4 __attribute__((ext_vector_type(4)));
typedef unsigned short u16x8 __attribute__((ext_vector_type(8)));
typedef unsigned short u16;

__device__ __forceinline__ u16 f2bf(float f) {
  unsigned u = __float_as_uint(f);
  unsigned r = 0x7fffu + ((u >> 16) & 1u);
  return (u16)((u + r) >> 16);
}
__device__ __forceinline__ float bf2f(u16 u) {
  return __uint_as_float(((unsigned)u) << 16);
}

// async global->LDS, 16B per lane; dest must be wave-uniform base + lane*16
__device__ __forceinline__ void gload16(const u16* g, u16* l) {
  __builtin_amdgcn_global_load_lds(
      (const __attribute__((address_space(1))) unsigned int*)g,
      (__attribute__((address_space(3))) unsigned int*)l, 16, 0, 0);
}

// ---------------- fp32 -> bf16 convert ----------------
__global__ __launch_bounds__(256) void cvt_kernel(const float* __restrict__ src,
                                                  u16* __restrict__ dst, int n) {
  int i = (blockIdx.x * 256 + threadIdx.x) * 8;
  if (i + 8 > n) return;
  float4 a = *reinterpret_cast<const float4*>(src + i);
  float4 b = *reinterpret_cast<const float4*>(src + i + 4);
  u16x8 o;
  o[0] = f2bf(a.x); o[1] = f2bf(a.y); o[2] = f2bf(a.z); o[3] = f2bf(a.w);
  o[4] = f2bf(b.x); o[5] = f2bf(b.y); o[6] = f2bf(b.z); o[7] = f2bf(b.w);
  *reinterpret_cast<u32x4*>(dst + i) = __builtin_bit_cast(u32x4, o);
}

// ---------------- GEMM: C[M][N] = A[M][K] * B[N][K]^T (bf16 in, fp32 acc) ----
// 128x128 tile, 4 waves (2x2), BK=32, global_load_lds staging (m97 structure).
template <int F32OUT>
__global__ __launch_bounds__(256) void gemm_bt(const u16* __restrict__ A,
                                               const u16* __restrict__ B,
                                               void* __restrict__ Cout,
                                               int M, int N, int K) {
  __shared__ u16 As[128 * 32];
  __shared__ u16 Bs[128 * 32];
  const int t = threadIdx.x;
  const int lane = t & 63;
  const int wave = t >> 6;
  const int wr = (wave >> 1) * 64;
  const int wc = (wave & 1) * 64;
  const int lrow = lane & 15;
  const int lk = (lane >> 4) * 8;
  const int bm = blockIdx.x * 128;
  const int bn = blockIdx.y * 128;
  const int r0 = t >> 2;       // staging row (0..63), +64 for issue 1
  const int c0 = (t & 3) * 8;  // staging col

  f32x4 acc[4][4] = {};

  for (int kt = 0; kt < K; kt += 32) {
#pragma unroll
    for (int is = 0; is < 2; ++is) {
      gload16(A + (size_t)(bm + is * 64 + r0) * K + kt + c0, &As[is * 2048 + t * 8]);
      gload16(B + (size_t)(bn + is * 64 + r0) * K + kt + c0, &Bs[is * 2048 + t * 8]);
    }
    __syncthreads();
    bf16x8 af[4], bfv[4];
#pragma unroll
    for (int m = 0; m < 4; ++m)
      af[m] = __builtin_bit_cast(bf16x8,
          *reinterpret_cast<const u32x4*>(&As[(wr + m * 16 + lrow) * 32 + lk]));
#pragma unroll
    for (int n = 0; n < 4; ++n)
      bfv[n] = __builtin_bit_cast(bf16x8,
          *reinterpret_cast<const u32x4*>(&Bs[(wc + n * 16 + lrow) * 32 + lk]));
#pragma unroll
    for (int m = 0; m < 4; ++m)
#pragma unroll
      for (int n = 0; n < 4; ++n)
        acc[m][n] = __builtin_amdgcn_mfma_f32_16x16x32_bf16(af[m], bfv[n], acc[m][n], 0, 0, 0);
    __syncthreads();
  }

  const int rbase = (lane >> 4) * 4;
#pragma unroll
  for (int m = 0; m < 4; ++m) {
#pragma unroll
    for (int n = 0; n < 4; ++n) {
#pragma unroll
      for (int r = 0; r < 4; ++r) {
        int row = bm + wr + m * 16 + rbase + r;
        int col = bn + wc + n * 16 + lrow;
        if (F32OUT)
          ((float*)Cout)[(size_t)row * N + col] = acc[m][n][r];
        else
          ((u16*)Cout)[(size_t)row * N + col] = f2bf(acc[m][n][r]);
      }
    }
  }
}

// ---------------- RoPE (in-place on bf16 [S][H] tensor) ----------------
__global__ __launch_bounds__(256) void rope_kernel(u16* __restrict__ X) {
  int idx = blockIdx.x * 256 + threadIdx.x;  // SEQ*NHEADS*64
  int i = idx & 63;
  int h = (idx >> 6) & (NHEADS - 1);
  int s = idx >> 10;
  if (s >= SEQ) return;
  float inv_freq = powf(10000.0f, -(float)i * (1.0f / 64.0f));
  float ang = (float)s * inv_freq;
  float c = cosf(ang), sn = sinf(ang);
  size_t base = (size_t)s * HIDDEN + h * HDIM + i;
  float x1 = bf2f(X[base]);
  float x2 = bf2f(X[base + 64]);
  X[base] = f2bf(x1 * c - x2 * sn);
  X[base + 64] = f2bf(x2 * c + x1 * sn);
}

// ---------------- causal flash attention ----------------
// grid (SEQ/QBLK, NHEADS); 4 waves, each owns 32 q-rows; KV tile 64 wide.
// K staged [64][128] u16 (row-swizzled), V^T staged [128][64] (row-swizzled).
__global__ __launch_bounds__(256, 2) void attn_kernel(const u16* __restrict__ Q,
                                                      const u16* __restrict__ Kg,
                                                      const u16* __restrict__ Vt,
                                                      u16* __restrict__ O) {
  __shared__ u16 Ks[KVB * 128];
  __shared__ u16 Vs[128 * KVB];
  __shared__ u16 Ps[4][WQ * KVB];
  const int t = threadIdx.x;
  const int wave = t >> 6;
  const int lane = t & 63;
  const int lrow = lane & 15;
  const int lgrp = lane >> 4;
  const int h = blockIdx.y;
  const int qtile = (int)gridDim.x - 1 - (int)blockIdx.x;  // heavy tiles first
  const int qb0 = qtile * QBLK;
  const int qw = qb0 + wave * WQ;

  // Q fragments: rows qw + rowf*16 + lrow, k-chunks of 32
  bf16x8 qf[2][4];
#pragma unroll
  for (int rowf = 0; rowf < 2; ++rowf)
#pragma unroll
    for (int kk = 0; kk < 4; ++kk)
      qf[rowf][kk] = __builtin_bit_cast(bf16x8, *reinterpret_cast<const u32x4*>(
          Q + (size_t)(qw + rowf * 16 + lrow) * HIDDEN + h * HDIM + kk * 32 + lgrp * 8));

  f32x4 acc[2][8] = {};
  float mrow[2][4], lsum[2][4];
#pragma unroll
  for (int i = 0; i < 2; ++i)
#pragma unroll
    for (int r = 0; r < 4; ++r) { mrow[i][r] = -1e30f; lsum[i][r] = 0.f; }

  const int nblk = (qb0 + QBLK) / KVB;
  for (int b = 0; b < nblk; ++b) {
    const int t0 = b * KVB;
    // stage K tile + Vt tile, swizzled via pre-swizzled global source (linear LDS dest)
#pragma unroll
    for (int is = 0; is < 4; ++is) {
      int ch = is * 256 + t;                 // 0..1023 chunks of 16B
      int krow = ch >> 4, kslot = ch & 15;   // K row 256B = 16 slots
      int kcol = ((kslot & 8) | ((kslot ^ krow) & 7)) * 8;
      gload16(Kg + (size_t)(t0 + krow) * HIDDEN + h * HDIM + kcol, &Ks[ch * 8]);
      int vrow = ch >> 3, vslot = ch & 7;    // Vt row 128B = 8 slots
      int vcol = ((vslot ^ vrow) & 7) * 8;
      gload16(Vt + (size_t)(h * HDIM + vrow) * SEQ + t0 + vcol, &Vs[ch * 8]);
    }
    __syncthreads();

    if (t0 <= qw + WQ - 1) {  // wave-uniform skip of fully-masked tiles
      const bool need_mask = (t0 + KVB - 1 > qw);
      // QK^T: 2 row-frags x 4 col-frags x 4 k-chunks
      f32x4 sc[2][4] = {};
#pragma unroll
      for (int kk = 0; kk < 4; ++kk) {
#pragma unroll
        for (int colf = 0; colf < 4; ++colf) {
          int trow = colf * 16 + lrow;
          int slot = kk * 4 + lgrp;
          bf16x8 kf = __builtin_bit_cast(bf16x8, *reinterpret_cast<const u32x4*>(
              &Ks[trow * 128 + ((slot & 8) | ((slot ^ trow) & 7)) * 8]));
#pragma unroll
          for (int rowf = 0; rowf < 2; ++rowf)
            sc[rowf][colf] = __builtin_amdgcn_mfma_f32_16x16x32_bf16(
                qf[rowf][kk], kf, sc[rowf][colf], 0, 0, 0);
        }
      }
      // scale + causal mask + row max
      float pm[2][4];
#pragma unroll
      for (int rowf = 0; rowf < 2; ++rowf)
#pragma unroll
        for (int r = 0; r < 4; ++r) {
          const int qg = qw + rowf * 16 + lgrp * 4 + r;
          float mx = -1e30f;
#pragma unroll
          for (int colf = 0; colf < 4; ++colf) {
            float v = sc[rowf][colf][r] * 0.088388347648318447f;
            if (need_mask) {
              int tg = t0 + colf * 16 + lrow;
              v = (tg <= qg) ? v : -1e30f;
            }
            sc[rowf][colf][r] = v;
            mx = fmaxf(mx, v);
          }
          pm[rowf][r] = mx;
        }
#pragma unroll
      for (int off = 1; off < 16; off <<= 1)
#pragma unroll
        for (int rowf = 0; rowf < 2; ++rowf)
#pragma unroll
          for (int r = 0; r < 4; ++r)
            pm[rowf][r] = fmaxf(pm[rowf][r], __shfl_xor(pm[rowf][r], off));

      // online softmax update
      float psum[2][4];
#pragma unroll
      for (int rowf = 0; rowf < 2; ++rowf)
#pragma unroll
        for (int r = 0; r < 4; ++r) {
          float mn = fmaxf(mrow[rowf][r], pm[rowf][r]);
          float sf = __expf(mrow[rowf][r] - mn);
          mrow[rowf][r] = mn;
          lsum[rowf][r] *= sf;
#pragma unroll
          for (int nn = 0; nn < 8; ++nn) acc[rowf][nn][r] *= sf;
          float ps = 0.f;
#pragma unroll
          for (int colf = 0; colf < 4; ++colf) {
            float p = __expf(sc[rowf][colf][r] - mn);
            sc[rowf][colf][r] = p;
            ps += p;
          }
          psum[rowf][r] = ps;
        }
#pragma unroll
      for (int off = 1; off < 16; off <<= 1)
#pragma unroll
        for (int rowf = 0; rowf < 2; ++rowf)
#pragma unroll
          for (int r = 0; r < 4; ++r)
            psum[rowf][r] += __shfl_xor(psum[rowf][r], off);
#pragma unroll
      for (int rowf = 0; rowf < 2; ++rowf)
#pragma unroll
        for (int r = 0; r < 4; ++r) lsum[rowf][r] += psum[rowf][r];

      // P -> LDS (bf16, swizzled rows of 64)
#pragma unroll
      for (int rowf = 0; rowf < 2; ++rowf)
#pragma unroll
        for (int colf = 0; colf < 4; ++colf) {
          int tloc = colf * 16 + lrow;
          int sb = tloc >> 3, tlo = tloc & 7;
#pragma unroll
          for (int r = 0; r < 4; ++r) {
            int ql = rowf * 16 + lgrp * 4 + r;
            Ps[wave][ql * 64 + ((sb ^ (ql & 7)) * 8) + tlo] = f2bf(sc[rowf][colf][r]);
          }
        }
      // PV: 2 k-steps x 8 d-frags, all ds_read_b128
#pragma unroll
      for (int ks = 0; ks < 2; ++ks) {
        bf16x8 pa[2];
#pragma unroll
        for (int rowf = 0; rowf < 2; ++rowf) {
          int q = rowf * 16 + lrow;
          pa[rowf] = __builtin_bit_cast(bf16x8, *reinterpret_cast<const u32x4*>(
              &Ps[wave][q * 64 + (((ks * 4 + lgrp) ^ (q & 7)) & 7) * 8]));
        }
#pragma unroll
        for (int nn = 0; nn < 8; ++nn) {
          int d = nn * 16 + lrow;
          bf16x8 vb = __builtin_bit_cast(bf16x8, *reinterpret_cast<const u32x4*>(
              &Vs[d * 64 + (((ks * 4 + lgrp) ^ d) & 7) * 8]));
#pragma unroll
          for (int rowf = 0; rowf < 2; ++rowf)
            acc[rowf][nn] = __builtin_amdgcn_mfma_f32_16x16x32_bf16(
                pa[rowf], vb, acc[rowf][nn], 0, 0, 0);
        }
      }
    }
    __syncthreads();
  }

  // epilogue
#pragma unroll
  for (int rowf = 0; rowf < 2; ++rowf)
#pragma unroll
    for (int nn = 0; nn < 8; ++nn)
#pragma unroll
      for (int r = 0; r < 4; ++r) {
        int row = qw + rowf * 16 + lgrp * 4 + r;
        int col = h * HDIM + nn * 16 + lrow;
        O[(size_t)row * HIDDEN + col] = f2bf(acc[rowf][nn][r] / lsum[rowf][r]);
      }
}

// ---------------- launch ----------------
extern "C" void kernel_launch(void* const* d_in, const int* in_sizes, int n_in,
                              void* d_out, int out_size, void* d_ws, size_t ws_size,
                              hipStream_t stream) {
  const float* X  = (const float*)d_in[0];
  const float* Wq = (const float*)d_in[1];
  const float* Wk = (const float*)d_in[2];
  const float* Wv = (const float*)d_in[3];
  const float* Wo = (const float*)d_in[4];
  float* out = (float*)d_out;

  u16* ws = (u16*)d_ws;
  const size_t SH = (size_t)SEQ * HIDDEN;
  const size_t HH = (size_t)HIDDEN * HIDDEN;
  u16* Xb  = ws;
  u16* Wqb = Xb + SH;
  u16* Wkb = Wqb + HH;
  u16* Wvb = Wkb + HH;
  u16* Wob = Wvb + HH;
  u16* Qb  = Wob + HH;
  u16* Kb  = Qb + SH;
  u16* Vtb = Kb + SH;   // V^T: [HIDDEN][SEQ]
  u16* Cb  = Vtb + SH;

  cvt_kernel<<<(int)(SH / 2048), 256, 0, stream>>>(X, Xb, (int)SH);
  cvt_kernel<<<(int)(HH / 2048), 256, 0, stream>>>(Wq, Wqb, (int)HH);
  cvt_kernel<<<(int)(HH / 2048), 256, 0, stream>>>(Wk, Wkb, (int)HH);
  cvt_kernel<<<(int)(HH / 2048), 256, 0, stream>>>(Wv, Wvb, (int)HH);
  cvt_kernel<<<(int)(HH / 2048), 256, 0, stream>>>(Wo, Wob, (int)HH);

  dim3 ggrid(SEQ / 128, HIDDEN / 128);
  gemm_bt<0><<<ggrid, 256, 0, stream>>>(Xb, Wqb, Qb, SEQ, HIDDEN, HIDDEN);
  gemm_bt<0><<<ggrid, 256, 0, stream>>>(Xb, Wkb, Kb, SEQ, HIDDEN, HIDDEN);
  // V projection computed TRANSPOSED: Vt[i][j] = Wv[i,:]·X[j,:] = V[j][i]
  gemm_bt<0><<<dim3(HIDDEN / 128, SEQ / 128), 256, 0, stream>>>(Wvb, Xb, Vtb, HIDDEN, SEQ, HIDDEN);

  const int ropeN = SEQ * NHEADS * 64;
  rope_kernel<<<ropeN / 256, 256, 0, stream>>>(Qb);
  rope_kernel<<<ropeN / 256, 256, 0, stream>>>(Kb);

  attn_kernel<<<dim3(SEQ / QBLK, NHEADS), 256, 0, stream>>>(Qb, Kb, Vtb, Cb);

  gemm_bt<1><<<ggrid, 256, 0, stream>>>(Cb, Wob, out, SEQ, HIDDEN, HIDDEN);
}

// Round 3
// 468.057 us; speedup vs baseline: 1.9799x; 1.2807x over previous
//
#include <hip/hip_runtime.h>

#define SEQ 4096
#define HIDDEN 2048
#define NHEADS 16
#define HDIM 128
#define QBLK 128
#define WQ 32
#define KVB 64

typedef float f32x4 __attribute__((ext_vector_type(4)));
typedef __bf16 bf16x8 __attribute__((ext_vector_type(8)));
typedef unsigned int u32x4 __attribute__((ext_vector_type(4)));
typedef unsigned short u16x8 __attribute__((ext_vector_type(8)));
typedef unsigned short u16x4 __attribute__((ext_vector_type(4)));
typedef unsigned short u16;

// 1/sqrt(128) * log2(e)  (softmax done in exp2 domain)
#define SCL2 0.12751747456918851f

__device__ __forceinline__ u16 f2bf(float f) {
  unsigned u = __float_as_uint(f);
  unsigned r = 0x7fffu + ((u >> 16) & 1u);
  return (u16)((u + r) >> 16);
}
__device__ __forceinline__ float bf2f(u16 u) {
  return __uint_as_float(((unsigned)u) << 16);
}

// async global->LDS, 16B per lane; dest must be wave-uniform base + lane*16
__device__ __forceinline__ void gload16(const u16* g, u16* l) {
  __builtin_amdgcn_global_load_lds(
      (const __attribute__((address_space(1))) unsigned int*)g,
      (__attribute__((address_space(3))) unsigned int*)l, 16, 0, 0);
}

// ---------------- fp32 -> bf16 convert ----------------
__global__ __launch_bounds__(256) void cvt_kernel(const float* __restrict__ src,
                                                  u16* __restrict__ dst, int n) {
  int i = (blockIdx.x * 256 + threadIdx.x) * 8;
  if (i + 8 > n) return;
  float4 a = *reinterpret_cast<const float4*>(src + i);
  float4 b = *reinterpret_cast<const float4*>(src + i + 4);
  u16x8 o;
  o[0] = f2bf(a.x); o[1] = f2bf(a.y); o[2] = f2bf(a.z); o[3] = f2bf(a.w);
  o[4] = f2bf(b.x); o[5] = f2bf(b.y); o[6] = f2bf(b.z); o[7] = f2bf(b.w);
  *reinterpret_cast<u32x4*>(dst + i) = __builtin_bit_cast(u32x4, o);
}

// ---------------- GEMM: C[M][N] = A[M][K] * B[N][K]^T (bf16 in, fp32 acc) ----
template <int F32OUT>
__global__ __launch_bounds__(256) void gemm_bt(const u16* __restrict__ A,
                                               const u16* __restrict__ B,
                                               void* __restrict__ Cout,
                                               int M, int N, int K) {
  __shared__ u16 As[128 * 32];
  __shared__ u16 Bs[128 * 32];
  const int t = threadIdx.x;
  const int lane = t & 63;
  const int wave = t >> 6;
  const int wr = (wave >> 1) * 64;
  const int wc = (wave & 1) * 64;
  const int lrow = lane & 15;
  const int lk = (lane >> 4) * 8;
  const int bm = blockIdx.x * 128;
  const int bn = blockIdx.y * 128;
  const int r0 = t >> 2;
  const int c0 = (t & 3) * 8;

  f32x4 acc[4][4] = {};

  for (int kt = 0; kt < K; kt += 32) {
#pragma unroll
    for (int is = 0; is < 2; ++is) {
      gload16(A + (size_t)(bm + is * 64 + r0) * K + kt + c0, &As[is * 2048 + t * 8]);
      gload16(B + (size_t)(bn + is * 64 + r0) * K + kt + c0, &Bs[is * 2048 + t * 8]);
    }
    __syncthreads();
    bf16x8 af[4], bfv[4];
#pragma unroll
    for (int m = 0; m < 4; ++m)
      af[m] = __builtin_bit_cast(bf16x8,
          *reinterpret_cast<const u32x4*>(&As[(wr + m * 16 + lrow) * 32 + lk]));
#pragma unroll
    for (int n = 0; n < 4; ++n)
      bfv[n] = __builtin_bit_cast(bf16x8,
          *reinterpret_cast<const u32x4*>(&Bs[(wc + n * 16 + lrow) * 32 + lk]));
#pragma unroll
    for (int m = 0; m < 4; ++m)
#pragma unroll
      for (int n = 0; n < 4; ++n)
        acc[m][n] = __builtin_amdgcn_mfma_f32_16x16x32_bf16(af[m], bfv[n], acc[m][n], 0, 0, 0);
    __syncthreads();
  }

  const int rbase = (lane >> 4) * 4;
#pragma unroll
  for (int m = 0; m < 4; ++m) {
#pragma unroll
    for (int n = 0; n < 4; ++n) {
#pragma unroll
      for (int r = 0; r < 4; ++r) {
        int row = bm + wr + m * 16 + rbase + r;
        int col = bn + wc + n * 16 + lrow;
        if (F32OUT)
          ((float*)Cout)[(size_t)row * N + col] = acc[m][n][r];
        else
          ((u16*)Cout)[(size_t)row * N + col] = f2bf(acc[m][n][r]);
      }
    }
  }
}

// ---------------- RoPE (in-place on bf16 [S][H] tensor) ----------------
__global__ __launch_bounds__(256) void rope_kernel(u16* __restrict__ X) {
  int idx = blockIdx.x * 256 + threadIdx.x;
  int i = idx & 63;
  int h = (idx >> 6) & (NHEADS - 1);
  int s = idx >> 10;
  if (s >= SEQ) return;
  float inv_freq = powf(10000.0f, -(float)i * (1.0f / 64.0f));
  float ang = (float)s * inv_freq;
  float c = cosf(ang), sn = sinf(ang);
  size_t base = (size_t)s * HIDDEN + h * HDIM + i;
  float x1 = bf2f(X[base]);
  float x2 = bf2f(X[base + 64]);
  X[base] = f2bf(x1 * c - x2 * sn);
  X[base + 64] = f2bf(x2 * c + x1 * sn);
}

// ---------------- causal flash attention ----------------
// 1-D grid of 512 blocks; balance remap pairs heavy+light q-tiles per CU.
// 4 waves/block, 32 q-rows/wave; KV tile 64; K/V double-buffered in LDS.
// Swapped QK^T: mfma(K,Q) -> lane holds scores for q-row (lane&15).
__global__ __launch_bounds__(256, 2) void attn_kernel(const u16* __restrict__ Q,
                                                      const u16* __restrict__ Kg,
                                                      const u16* __restrict__ Vt,
                                                      u16* __restrict__ O) {
  __shared__ u16 Ks[2][KVB * 128];
  __shared__ u16 Vs[2][128 * KVB];
  __shared__ u16 Ps[4][WQ * KVB];
  const int t = threadIdx.x;
  const int wave = t >> 6;
  const int lane = t & 63;
  const int lrow = lane & 15;
  const int lgrp = lane >> 4;

  const int b = blockIdx.x;           // 0..511
  const int j = b & 255;
  const int h = j >> 4;
  const int qtile = (b < 256) ? (31 - (j & 15)) : (j & 15);
  const int qb0 = qtile * QBLK;
  const int qw = qb0 + wave * WQ;

  // Q fragments (B-operand of swapped QK): lane holds Q[qw+rowf*16+lrow][k-slice]
  bf16x8 qf[2][4];
#pragma unroll
  for (int rowf = 0; rowf < 2; ++rowf)
#pragma unroll
    for (int kk = 0; kk < 4; ++kk)
      qf[rowf][kk] = __builtin_bit_cast(bf16x8, *reinterpret_cast<const u32x4*>(
          Q + (size_t)(qw + rowf * 16 + lrow) * HIDDEN + h * HDIM + kk * 32 + lgrp * 8));

  // precomputed staging addresses (4 chunks of 16B per thread for K and for Vt)
  const u16* kgb[4]; const u16* vgb[4]; int kof[4], vof[4];
#pragma unroll
  for (int is = 0; is < 4; ++is) {
    int ch = is * 256 + t;
    int krow = ch >> 4, kslot = ch & 15;
    int kcol = ((kslot & 8) | ((kslot ^ krow) & 7)) * 8;
    kgb[is] = Kg + (size_t)krow * HIDDEN + h * HDIM + kcol;
    kof[is] = ch * 8;
    int vrow = ch >> 3, vslot = ch & 7;
    int vcol = ((vslot ^ vrow) & 7) * 8;
    vgb[is] = Vt + (size_t)(h * HDIM + vrow) * SEQ + vcol;
    vof[is] = ch * 8;
  }

  f32x4 acc[2][8] = {};
  float m2[2] = {-1e30f, -1e30f};
  float lsum[2] = {0.f, 0.f};

  const int nblk = 2 * qtile + 2;

  // prologue: stage tile 0 into buffer 0
#pragma unroll
  for (int is = 0; is < 4; ++is) {
    gload16(kgb[is], &Ks[0][kof[is]]);
    gload16(vgb[is], &Vs[0][vof[is]]);
  }
  __syncthreads();

  int cur = 0;
  for (int bt = 0; bt < nblk; ++bt) {
    const int t0 = bt * KVB;
    // prefetch next tile into the other buffer (overlaps with compute below)
    if (bt + 1 < nblk) {
      const int t1 = t0 + KVB;
#pragma unroll
      for (int is = 0; is < 4; ++is) {
        gload16(kgb[is] + (size_t)t1 * HIDDEN, &Ks[cur ^ 1][kof[is]]);
        gload16(vgb[is] + t1, &Vs[cur ^ 1][vof[is]]);
      }
    }

    if (t0 <= qw + WQ - 1) {  // wave-uniform skip of fully-masked tiles
      const bool need_mask = (t0 + KVB - 1 > qw);
      // QK^T swapped: sc[rowf][colf] reg r -> q = qw+rowf*16+lrow,
      //                                       kv = t0+colf*16+lgrp*4+r
      f32x4 sc[2][4] = {};
      __builtin_amdgcn_s_setprio(1);
#pragma unroll
      for (int kk = 0; kk < 4; ++kk) {
#pragma unroll
        for (int colf = 0; colf < 4; ++colf) {
          int trow = colf * 16 + lrow;
          int slot = kk * 4 + lgrp;
          bf16x8 kf = __builtin_bit_cast(bf16x8, *reinterpret_cast<const u32x4*>(
              &Ks[cur][trow * 128 + ((slot & 8) | ((slot ^ trow) & 7)) * 8]));
#pragma unroll
          for (int rowf = 0; rowf < 2; ++rowf)
            sc[rowf][colf] = __builtin_amdgcn_mfma_f32_16x16x32_bf16(
                kf, qf[rowf][kk], sc[rowf][colf], 0, 0, 0);
        }
      }
      __builtin_amdgcn_s_setprio(0);

      // scale (exp2 domain) + causal mask + in-lane row max
      float pmax[2];
#pragma unroll
      for (int rowf = 0; rowf < 2; ++rowf) {
        const int q = qw + rowf * 16 + lrow;
        float mx = -3.0e38f;
#pragma unroll
        for (int colf = 0; colf < 4; ++colf) {
          const int kvb0 = t0 + colf * 16 + lgrp * 4;
#pragma unroll
          for (int r = 0; r < 4; ++r) {
            float v = sc[rowf][colf][r] * SCL2;
            if (need_mask) v = (kvb0 + r <= q) ? v : -1e30f;
            sc[rowf][colf][r] = v;
            mx = fmaxf(mx, v);
          }
        }
        mx = fmaxf(mx, __shfl_xor(mx, 16));
        mx = fmaxf(mx, __shfl_xor(mx, 32));
        pmax[rowf] = mx;
      }

      // defer-max: rescale only when max grew by > 11.5 (2^11.5 ~ e^8)
      bool grow = (pmax[0] > m2[0] + 11.5f) || (pmax[1] > m2[1] + 11.5f);
      if (__any(grow)) {
#pragma unroll
        for (int rowf = 0; rowf < 2; ++rowf) {
          float mn = fmaxf(m2[rowf], pmax[rowf]);
          float sf = exp2f(m2[rowf] - mn);
          m2[rowf] = mn;
          lsum[rowf] *= sf;
#pragma unroll
          for (int r = 0; r < 4; ++r) {
            float sfr = __shfl(sf, (lane & 48) | (lgrp * 4 + r));
#pragma unroll
            for (int nn = 0; nn < 8; ++nn) acc[rowf][nn][r] *= sfr;
          }
        }
      }

      // exp2 + row-sum + P -> LDS (8B packed writes, swizzled)
#pragma unroll
      for (int rowf = 0; rowf < 2; ++rowf) {
        const int q = rowf * 16 + lrow;
        float ps = 0.f;
#pragma unroll
        for (int colf = 0; colf < 4; ++colf) {
          u16x4 pq;
#pragma unroll
          for (int r = 0; r < 4; ++r) {
            float p = exp2f(sc[rowf][colf][r] - m2[rowf]);
            ps += p;
            pq[r] = f2bf(p);
          }
          const int kv = colf * 16 + lgrp * 4;
          const int sw = (kv >> 3) ^ (q & 7);
          *reinterpret_cast<u16x4*>(&Ps[wave][q * 64 + sw * 8 + (kv & 7)]) = pq;
        }
        ps += __shfl_xor(ps, 16);
        ps += __shfl_xor(ps, 32);
        lsum[rowf] += ps;
      }

      // PV: P (A-op, lane-local rows) x V^T tiles
      __builtin_amdgcn_s_setprio(1);
#pragma unroll
      for (int ks = 0; ks < 2; ++ks) {
        bf16x8 pa[2];
#pragma unroll
        for (int rowf = 0; rowf < 2; ++rowf) {
          const int q = rowf * 16 + lrow;
          const int sl = ks * 4 + lgrp;
          pa[rowf] = __builtin_bit_cast(bf16x8, *reinterpret_cast<const u32x4*>(
              &Ps[wave][q * 64 + (sl ^ (q & 7)) * 8]));
        }
#pragma unroll
        for (int nn = 0; nn < 8; ++nn) {
          const int d = nn * 16 + lrow;
          bf16x8 vb = __builtin_bit_cast(bf16x8, *reinterpret_cast<const u32x4*>(
              &Vs[cur][d * 64 + (((ks * 4 + lgrp) ^ d) & 7) * 8]));
#pragma unroll
          for (int rowf = 0; rowf < 2; ++rowf)
            acc[rowf][nn] = __builtin_amdgcn_mfma_f32_16x16x32_bf16(
                pa[rowf], vb, acc[rowf][nn], 0, 0, 0);
        }
      }
      __builtin_amdgcn_s_setprio(0);
    }

    __syncthreads();  // compiler drains vmcnt(0): next buffer ready for all
    cur ^= 1;
  }

  // epilogue: redistribute lsum to acc layout, divide, store
#pragma unroll
  for (int rowf = 0; rowf < 2; ++rowf) {
    float inv[4];
#pragma unroll
    for (int r = 0; r < 4; ++r) {
      float lsr = __shfl(lsum[rowf], (lane & 48) | (lgrp * 4 + r));
      inv[r] = 1.0f / lsr;
    }
#pragma unroll
    for (int nn = 0; nn < 8; ++nn)
#pragma unroll
      for (int r = 0; r < 4; ++r) {
        int row = qw + rowf * 16 + lgrp * 4 + r;
        int col = h * HDIM + nn * 16 + lrow;
        O[(size_t)row * HIDDEN + col] = f2bf(acc[rowf][nn][r] * inv[r]);
      }
  }
}

// ---------------- launch ----------------
extern "C" void kernel_launch(void* const* d_in, const int* in_sizes, int n_in,
                              void* d_out, int out_size, void* d_ws, size_t ws_size,
                              hipStream_t stream) {
  const float* X  = (const float*)d_in[0];
  const float* Wq = (const float*)d_in[1];
  const float* Wk = (const float*)d_in[2];
  const float* Wv = (const float*)d_in[3];
  const float* Wo = (const float*)d_in[4];
  float* out = (float*)d_out;

  u16* ws = (u16*)d_ws;
  const size_t SH = (size_t)SEQ * HIDDEN;
  const size_t HH = (size_t)HIDDEN * HIDDEN;
  u16* Xb  = ws;
  u16* Wqb = Xb + SH;
  u16* Wkb = Wqb + HH;
  u16* Wvb = Wkb + HH;
  u16* Wob = Wvb + HH;
  u16* Qb  = Wob + HH;
  u16* Kb  = Qb + SH;
  u16* Vtb = Kb + SH;   // V^T: [HIDDEN][SEQ]
  u16* Cb  = Vtb + SH;

  cvt_kernel<<<(int)(SH / 2048), 256, 0, stream>>>(X, Xb, (int)SH);
  cvt_kernel<<<(int)(HH / 2048), 256, 0, stream>>>(Wq, Wqb, (int)HH);
  cvt_kernel<<<(int)(HH / 2048), 256, 0, stream>>>(Wk, Wkb, (int)HH);
  cvt_kernel<<<(int)(HH / 2048), 256, 0, stream>>>(Wv, Wvb, (int)HH);
  cvt_kernel<<<(int)(HH / 2048), 256, 0, stream>>>(Wo, Wob, (int)HH);

  dim3 ggrid(SEQ / 128, HIDDEN / 128);
  gemm_bt<0><<<ggrid, 256, 0, stream>>>(Xb, Wqb, Qb, SEQ, HIDDEN, HIDDEN);
  gemm_bt<0><<<ggrid, 256, 0, stream>>>(Xb, Wkb, Kb, SEQ, HIDDEN, HIDDEN);
  // V projection computed TRANSPOSED: Vt[i][j] = Wv[i,:]·X[j,:] = V[j][i]
  gemm_bt<0><<<dim3(HIDDEN / 128, SEQ / 128), 256, 0, stream>>>(Wvb, Xb, Vtb, HIDDEN, SEQ, HIDDEN);

  const int ropeN = SEQ * NHEADS * 64;
  rope_kernel<<<ropeN / 256, 256, 0, stream>>>(Qb);
  rope_kernel<<<ropeN / 256, 256, 0, stream>>>(Kb);

  attn_kernel<<<512, 256, 0, stream>>>(Qb, Kb, Vtb, Cb);

  gemm_bt<1><<<ggrid, 256, 0, stream>>>(Cb, Wob, out, SEQ, HIDDEN, HIDDEN);
}

// Round 4
// 375.959 us; speedup vs baseline: 2.4650x; 1.2450x over previous
//
#include <hip/hip_runtime.h>

#define SEQ 4096
#define HIDDEN 2048
#define NHEADS 16
#define HDIM 128
#define QBLK 128
#define WQ 32
#define KVB 64

typedef float f32x4 __attribute__((ext_vector_type(4)));
typedef __bf16 bf16x8 __attribute__((ext_vector_type(8)));
typedef unsigned int u32x4 __attribute__((ext_vector_type(4)));
typedef unsigned int u32x2 __attribute__((ext_vector_type(2)));
typedef unsigned short u16x8 __attribute__((ext_vector_type(8)));
typedef unsigned short u16x4 __attribute__((ext_vector_type(4)));
typedef unsigned short u16;

// 1/sqrt(128) * log2(e)  (softmax in exp2 domain)
#define SCL2 0.12751747456918851f
// log2(10000)/64
#define RLOG 0.2076205059304601f

__device__ __forceinline__ u16 f2bf(float f) {
  unsigned u = __float_as_uint(f);
  unsigned r = 0x7fffu + ((u >> 16) & 1u);
  return (u16)((u + r) >> 16);
}
__device__ __forceinline__ unsigned cvtpk(float a, float b) {
  unsigned r;
  asm volatile("v_cvt_pk_bf16_f32 %0, %1, %2" : "=v"(r) : "v"(a), "v"(b));
  return r;
}

// async global->LDS, 16B per lane; dest = wave-uniform base + lane*16
__device__ __forceinline__ void gload16(const u16* g, u16* l) {
  __builtin_amdgcn_global_load_lds(
      (const __attribute__((address_space(1))) unsigned int*)g,
      (__attribute__((address_space(3))) unsigned int*)l, 16, 0, 0);
}

// ---------------- fp32 -> bf16 convert (all 5 inputs, one launch) ----------
__global__ __launch_bounds__(256) void cvt5(const float* __restrict__ X,
    const float* __restrict__ Wq, const float* __restrict__ Wk,
    const float* __restrict__ Wv, const float* __restrict__ Wo,
    u16* __restrict__ dst) {
  const size_t SH = (size_t)SEQ * HIDDEN, HH = (size_t)HIDDEN * HIDDEN;
  size_t i = ((size_t)blockIdx.x * 256 + threadIdx.x) * 8;
  const float* src; size_t off;
  if (i < SH) { src = X; off = i; }
  else if (i < SH + HH) { src = Wq; off = i - SH; }
  else if (i < SH + 2 * HH) { src = Wk; off = i - SH - HH; }
  else if (i < SH + 3 * HH) { src = Wv; off = i - SH - 2 * HH; }
  else { src = Wo; off = i - SH - 3 * HH; }
  float4 a = *reinterpret_cast<const float4*>(src + off);
  float4 b = *reinterpret_cast<const float4*>(src + off + 4);
  u16x8 o;
  o[0] = f2bf(a.x); o[1] = f2bf(a.y); o[2] = f2bf(a.z); o[3] = f2bf(a.w);
  o[4] = f2bf(b.x); o[5] = f2bf(b.y); o[6] = f2bf(b.z); o[7] = f2bf(b.w);
  *reinterpret_cast<u32x4*>(dst + i) = __builtin_bit_cast(u32x4, o);
}

// ---------------- fused QKV GEMM (+RoPE epilogue for Q,K) -------------------
// 1536 blocks: z=0 Q, z=1 K (4096x2048, rope), z=2 V^T (2048x4096, no rope).
// 128x128 tile, 4 waves each owning 32 rows x 128 cols, BK=32, LDS dbuf,
// one barrier per K-step, XCD-swizzled 1-D grid.
__global__ __launch_bounds__(256, 3) void gemm_qkv(const u16* __restrict__ Xb,
    const u16* __restrict__ Wqb, const u16* __restrict__ Wkb,
    const u16* __restrict__ Wvb, u16* __restrict__ Qo, u16* __restrict__ Ko,
    u16* __restrict__ Vt) {
  __shared__ u16 As[2][128 * 32];
  __shared__ u16 Bs[2][128 * 32];
  const int wg = blockIdx.x;
  const int swz = (wg & 7) * 192 + (wg >> 3);   // 1536 = 8*192, bijective
  const int z = swz >> 9;
  const int rr_ = swz & 511;
  const u16 *A, *B;
  u16* C;
  int bm, bn, cst;
  if (z == 2) {
    A = Wvb; B = Xb; C = Vt;
    bm = (rr_ & 15) << 7; bn = (rr_ >> 4) << 7; cst = SEQ;
  } else {
    A = Xb; B = z ? Wkb : Wqb; C = z ? Ko : Qo;
    bm = (rr_ & 31) << 7; bn = (rr_ >> 5) << 7; cst = HIDDEN;
  }
  const int t = threadIdx.x, lane = t & 63, wave = t >> 6;
  const int lrow = lane & 15, lk = (lane >> 4) * 8;
  const int wr = wave * 32;
  const int r0 = t >> 2, c0 = (t & 3) * 8;

  f32x4 acc[2][8] = {};

#pragma unroll
  for (int is = 0; is < 2; ++is) {
    gload16(A + (size_t)(bm + is * 64 + r0) * HIDDEN + c0, &As[0][is * 2048 + t * 8]);
    gload16(B + (size_t)(bn + is * 64 + r0) * HIDDEN + c0, &Bs[0][is * 2048 + t * 8]);
  }
  __syncthreads();

  int p = 0;
  for (int kt = 0; kt < HIDDEN; kt += 32) {
    if (kt + 32 < HIDDEN) {
#pragma unroll
      for (int is = 0; is < 2; ++is) {
        gload16(A + (size_t)(bm + is * 64 + r0) * HIDDEN + kt + 32 + c0,
                &As[p ^ 1][is * 2048 + t * 8]);
        gload16(B + (size_t)(bn + is * 64 + r0) * HIDDEN + kt + 32 + c0,
                &Bs[p ^ 1][is * 2048 + t * 8]);
      }
    }
    bf16x8 af[2], bfv[8];
#pragma unroll
    for (int m = 0; m < 2; ++m)
      af[m] = __builtin_bit_cast(bf16x8,
          *reinterpret_cast<const u32x4*>(&As[p][(wr + m * 16 + lrow) * 32 + lk]));
#pragma unroll
    for (int n = 0; n < 8; ++n)
      bfv[n] = __builtin_bit_cast(bf16x8,
          *reinterpret_cast<const u32x4*>(&Bs[p][(n * 16 + lrow) * 32 + lk]));
#pragma unroll
    for (int n = 0; n < 8; ++n)
#pragma unroll
      for (int m = 0; m < 2; ++m)
        acc[m][n] = __builtin_amdgcn_mfma_f32_16x16x32_bf16(af[m], bfv[n], acc[m][n], 0, 0, 0);
    __syncthreads();
    p ^= 1;
  }

  const int rb = (lane >> 4) * 4;
  if (z < 2) {  // RoPE on f32 accumulator: lane holds col pairs (i, i+64)
#pragma unroll
    for (int m = 0; m < 2; ++m)
#pragma unroll
      for (int q = 0; q < 4; ++q) {
        const int s = bm + wr + m * 16 + rb + q;
#pragma unroll
        for (int n = 0; n < 4; ++n) {
          const int ii = n * 16 + lrow;
          float inv = exp2f((float)ii * -RLOG);
          float ang = (float)s * inv;
          float sn, cs;
          __sincosf(ang, &sn, &cs);
          float x1 = acc[m][n][q], x2 = acc[m][n + 4][q];
          acc[m][n][q] = x1 * cs - x2 * sn;
          acc[m][n + 4][q] = x2 * cs + x1 * sn;
        }
      }
  }
#pragma unroll
  for (int m = 0; m < 2; ++m)
#pragma unroll
    for (int n = 0; n < 8; ++n)
#pragma unroll
      for (int q = 0; q < 4; ++q)
        C[(size_t)(bm + wr + m * 16 + rb + q) * cst + bn + n * 16 + lrow] =
            f2bf(acc[m][n][q]);
}

// ---------------- output GEMM: out = Cb * Wo^T (f32 out) --------------------
__global__ __launch_bounds__(256, 3) void gemm_out(const u16* __restrict__ A,
    const u16* __restrict__ B, float* __restrict__ C) {
  __shared__ u16 As[2][128 * 32];
  __shared__ u16 Bs[2][128 * 32];
  const int wg = blockIdx.x;
  const int swz = (wg & 7) * 64 + (wg >> 3);    // 512 = 8*64
  const int bm = (swz & 31) << 7;
  const int bn = (swz >> 5) << 7;
  const int t = threadIdx.x, lane = t & 63, wave = t >> 6;
  const int lrow = lane & 15, lk = (lane >> 4) * 8;
  const int wr = wave * 32;
  const int r0 = t >> 2, c0 = (t & 3) * 8;

  f32x4 acc[2][8] = {};

#pragma unroll
  for (int is = 0; is < 2; ++is) {
    gload16(A + (size_t)(bm + is * 64 + r0) * HIDDEN + c0, &As[0][is * 2048 + t * 8]);
    gload16(B + (size_t)(bn + is * 64 + r0) * HIDDEN + c0, &Bs[0][is * 2048 + t * 8]);
  }
  __syncthreads();

  int p = 0;
  for (int kt = 0; kt < HIDDEN; kt += 32) {
    if (kt + 32 < HIDDEN) {
#pragma unroll
      for (int is = 0; is < 2; ++is) {
        gload16(A + (size_t)(bm + is * 64 + r0) * HIDDEN + kt + 32 + c0,
                &As[p ^ 1][is * 2048 + t * 8]);
        gload16(B + (size_t)(bn + is * 64 + r0) * HIDDEN + kt + 32 + c0,
                &Bs[p ^ 1][is * 2048 + t * 8]);
      }
    }
    bf16x8 af[2], bfv[8];
#pragma unroll
    for (int m = 0; m < 2; ++m)
      af[m] = __builtin_bit_cast(bf16x8,
          *reinterpret_cast<const u32x4*>(&As[p][(wr + m * 16 + lrow) * 32 + lk]));
#pragma unroll
    for (int n = 0; n < 8; ++n)
      bfv[n] = __builtin_bit_cast(bf16x8,
          *reinterpret_cast<const u32x4*>(&Bs[p][(n * 16 + lrow) * 32 + lk]));
#pragma unroll
    for (int n = 0; n < 8; ++n)
#pragma unroll
      for (int m = 0; m < 2; ++m)
        acc[m][n] = __builtin_amdgcn_mfma_f32_16x16x32_bf16(af[m], bfv[n], acc[m][n], 0, 0, 0);
    __syncthreads();
    p ^= 1;
  }

  const int rb = (lane >> 4) * 4;
#pragma unroll
  for (int m = 0; m < 2; ++m)
#pragma unroll
    for (int n = 0; n < 8; ++n)
#pragma unroll
      for (int q = 0; q < 4; ++q)
        C[(size_t)(bm + wr + m * 16 + rb + q) * HIDDEN + bn + n * 16 + lrow] =
            acc[m][n][q];
}

// ---------------- causal flash attention ----------------
__global__ __launch_bounds__(256, 2) void attn_kernel(const u16* __restrict__ Q,
                                                      const u16* __restrict__ Kg,
                                                      const u16* __restrict__ Vt,
                                                      u16* __restrict__ O) {
  __shared__ u16 Ks[2][KVB * 128];
  __shared__ u16 Vs[2][128 * KVB];
  __shared__ u16 Ps[4][WQ * KVB];
  const int t = threadIdx.x;
  const int wave = t >> 6;
  const int lane = t & 63;
  const int lrow = lane & 15;
  const int lgrp = lane >> 4;

  const int b = blockIdx.x;           // 0..511
  const int j = b & 255;
  const int h = j >> 4;
  const int qtile = (b < 256) ? (31 - (j & 15)) : (j & 15);
  const int qb0 = qtile * QBLK;
  const int qw = qb0 + wave * WQ;

  bf16x8 qf[2][4];
#pragma unroll
  for (int rowf = 0; rowf < 2; ++rowf)
#pragma unroll
    for (int kk = 0; kk < 4; ++kk)
      qf[rowf][kk] = __builtin_bit_cast(bf16x8, *reinterpret_cast<const u32x4*>(
          Q + (size_t)(qw + rowf * 16 + lrow) * HIDDEN + h * HDIM + kk * 32 + lgrp * 8));

  const u16* kgb[4]; const u16* vgb[4]; int kof[4], vof[4];
#pragma unroll
  for (int is = 0; is < 4; ++is) {
    int ch = is * 256 + t;
    int krow = ch >> 4, kslot = ch & 15;
    int kcol = ((kslot & 8) | ((kslot ^ krow) & 7)) * 8;
    kgb[is] = Kg + (size_t)krow * HIDDEN + h * HDIM + kcol;
    kof[is] = ch * 8;
    int vrow = ch >> 3, vslot = ch & 7;
    int vcol = ((vslot ^ vrow) & 7) * 8;
    vgb[is] = Vt + (size_t)(h * HDIM + vrow) * SEQ + vcol;
    vof[is] = ch * 8;
  }

  f32x4 acc[2][8] = {};
  float m2[2] = {-1e30f, -1e30f};
  float lsum[2] = {0.f, 0.f};

  const int nblk = 2 * qtile + 2;

#pragma unroll
  for (int is = 0; is < 4; ++is) {
    gload16(kgb[is], &Ks[0][kof[is]]);
    gload16(vgb[is], &Vs[0][vof[is]]);
  }
  __syncthreads();

  int cur = 0;
  for (int bt = 0; bt < nblk; ++bt) {
    const int t0 = bt * KVB;
    if (bt + 1 < nblk) {
      const int t1 = t0 + KVB;
#pragma unroll
      for (int is = 0; is < 4; ++is) {
        gload16(kgb[is] + (size_t)t1 * HIDDEN, &Ks[cur ^ 1][kof[is]]);
        gload16(vgb[is] + t1, &Vs[cur ^ 1][vof[is]]);
      }
    }

    if (t0 <= qw + WQ - 1) {
      const bool need_mask = (t0 + KVB - 1 > qw);
      f32x4 sc[2][4] = {};
      __builtin_amdgcn_s_setprio(1);
#pragma unroll
      for (int kk = 0; kk < 4; ++kk) {
#pragma unroll
        for (int colf = 0; colf < 4; ++colf) {
          int trow = colf * 16 + lrow;
          int slot = kk * 4 + lgrp;
          bf16x8 kf = __builtin_bit_cast(bf16x8, *reinterpret_cast<const u32x4*>(
              &Ks[cur][trow * 128 + ((slot & 8) | ((slot ^ trow) & 7)) * 8]));
#pragma unroll
          for (int rowf = 0; rowf < 2; ++rowf)
            sc[rowf][colf] = __builtin_amdgcn_mfma_f32_16x16x32_bf16(
                kf, qf[rowf][kk], sc[rowf][colf], 0, 0, 0);
        }
      }
      __builtin_amdgcn_s_setprio(0);

      float pmax[2];
#pragma unroll
      for (int rowf = 0; rowf < 2; ++rowf) {
        const int q = qw + rowf * 16 + lrow;
        float mx = -3.0e38f;
#pragma unroll
        for (int colf = 0; colf < 4; ++colf) {
          const int kvb0 = t0 + colf * 16 + lgrp * 4;
#pragma unroll
          for (int r = 0; r < 4; ++r) {
            float v = sc[rowf][colf][r] * SCL2;
            if (need_mask) v = (kvb0 + r <= q) ? v : -1e30f;
            sc[rowf][colf][r] = v;
            mx = fmaxf(mx, v);
          }
        }
        mx = fmaxf(mx, __shfl_xor(mx, 16));
        mx = fmaxf(mx, __shfl_xor(mx, 32));
        pmax[rowf] = mx;
      }

      bool grow = (pmax[0] > m2[0] + 11.5f) || (pmax[1] > m2[1] + 11.5f);
      if (__any(grow)) {
#pragma unroll
        for (int rowf = 0; rowf < 2; ++rowf) {
          float mn = fmaxf(m2[rowf], pmax[rowf]);
          float sf = exp2f(m2[rowf] - mn);
          m2[rowf] = mn;
          lsum[rowf] *= sf;
#pragma unroll
          for (int r = 0; r < 4; ++r) {
            float sfr = __shfl(sf, (lane & 48) | (lgrp * 4 + r));
#pragma unroll
            for (int nn = 0; nn < 8; ++nn) acc[rowf][nn][r] *= sfr;
          }
        }
      }

#pragma unroll
      for (int rowf = 0; rowf < 2; ++rowf) {
        const int q = rowf * 16 + lrow;
        float ps = 0.f;
#pragma unroll
        for (int colf = 0; colf < 4; ++colf) {
          float pv[4];
#pragma unroll
          for (int r = 0; r < 4; ++r) {
            pv[r] = exp2f(sc[rowf][colf][r] - m2[rowf]);
            ps += pv[r];
          }
          u32x2 pk2;
          pk2[0] = cvtpk(pv[0], pv[1]);
          pk2[1] = cvtpk(pv[2], pv[3]);
          const int kv = colf * 16 + lgrp * 4;
          const int sw = (kv >> 3) ^ (q & 7);
          *reinterpret_cast<u32x2*>(&Ps[wave][q * 64 + sw * 8 + (kv & 7)]) = pk2;
        }
        ps += __shfl_xor(ps, 16);
        ps += __shfl_xor(ps, 32);
        lsum[rowf] += ps;
      }

      __builtin_amdgcn_s_setprio(1);
#pragma unroll
      for (int ks = 0; ks < 2; ++ks) {
        bf16x8 pa[2];
#pragma unroll
        for (int rowf = 0; rowf < 2; ++rowf) {
          const int q = rowf * 16 + lrow;
          const int sl = ks * 4 + lgrp;
          pa[rowf] = __builtin_bit_cast(bf16x8, *reinterpret_cast<const u32x4*>(
              &Ps[wave][q * 64 + (sl ^ (q & 7)) * 8]));
        }
#pragma unroll
        for (int nn = 0; nn < 8; ++nn) {
          const int d = nn * 16 + lrow;
          bf16x8 vb = __builtin_bit_cast(bf16x8, *reinterpret_cast<const u32x4*>(
              &Vs[cur][d * 64 + (((ks * 4 + lgrp) ^ d) & 7) * 8]));
#pragma unroll
          for (int rowf = 0; rowf < 2; ++rowf)
            acc[rowf][nn] = __builtin_amdgcn_mfma_f32_16x16x32_bf16(
                pa[rowf], vb, acc[rowf][nn], 0, 0, 0);
        }
      }
      __builtin_amdgcn_s_setprio(0);
    }

    __syncthreads();
    cur ^= 1;
  }

#pragma unroll
  for (int rowf = 0; rowf < 2; ++rowf) {
    float inv[4];
#pragma unroll
    for (int r = 0; r < 4; ++r) {
      float lsr = __shfl(lsum[rowf], (lane & 48) | (lgrp * 4 + r));
      inv[r] = 1.0f / lsr;
    }
#pragma unroll
    for (int nn = 0; nn < 8; ++nn)
#pragma unroll
      for (int r = 0; r < 4; ++r) {
        int row = qw + rowf * 16 + lgrp * 4 + r;
        int col = h * HDIM + nn * 16 + lrow;
        O[(size_t)row * HIDDEN + col] = f2bf(acc[rowf][nn][r] * inv[r]);
      }
  }
}

// ---------------- launch ----------------
extern "C" void kernel_launch(void* const* d_in, const int* in_sizes, int n_in,
                              void* d_out, int out_size, void* d_ws, size_t ws_size,
                              hipStream_t stream) {
  const float* X  = (const float*)d_in[0];
  const float* Wq = (const float*)d_in[1];
  const float* Wk = (const float*)d_in[2];
  const float* Wv = (const float*)d_in[3];
  const float* Wo = (const float*)d_in[4];
  float* out = (float*)d_out;

  u16* ws = (u16*)d_ws;
  const size_t SH = (size_t)SEQ * HIDDEN;
  const size_t HH = (size_t)HIDDEN * HIDDEN;
  u16* Xb  = ws;
  u16* Wqb = Xb + SH;
  u16* Wkb = Wqb + HH;
  u16* Wvb = Wkb + HH;
  u16* Wob = Wvb + HH;
  u16* Qb  = Wob + HH;
  u16* Kb  = Qb + SH;
  u16* Vtb = Kb + SH;   // V^T: [HIDDEN][SEQ]
  u16* Cb  = Vtb + SH;

  cvt5<<<(int)((SH + 4 * HH) / 2048), 256, 0, stream>>>(X, Wq, Wk, Wv, Wo, ws);

  gemm_qkv<<<1536, 256, 0, stream>>>(Xb, Wqb, Wkb, Wvb, Qb, Kb, Vtb);

  attn_kernel<<<512, 256, 0, stream>>>(Qb, Kb, Vtb, Cb);

  gemm_out<<<512, 256, 0, stream>>>(Cb, Wob, out);
}